// Round 7
// baseline (4410.549 us; speedup 1.0000x reference)
//
#include <hip/hip_runtime.h>
#include <math.h>

#define NN 50000
#define NE 600000
#define DIM 128
#define LAYERS 3
#define BN_EPS 1e-5f

#define SC_ELE 2048
#define NSCAN ((NN + SC_ELE - 1) / SC_ELE)   // 25 scan blocks
#define TM 32
#define KH 64                                 // K-half staged in LDS

// ---------------------------------------------------------------- init ----
__global__ void k_init(int* __restrict__ deg, float* __restrict__ bnstats) {
    int i = blockIdx.x * 256 + threadIdx.x;
    if (i < NN) deg[i] = 0;
    if (i < LAYERS * 2 * DIM) bnstats[i] = 0.0f;
}

// ----------------------------------------------------------- histogram ----
__global__ void k_hist(const int* __restrict__ dst, int* __restrict__ deg) {
    int e = blockIdx.x * 256 + threadIdx.x;
    if (e < NE) atomicAdd(&deg[dst[e]], 1);
}

// ------------------------------------------- hierarchical scan, pass 1 ----
__global__ __launch_bounds__(1024) void k_scan1(const int* __restrict__ deg,
                                                int* __restrict__ part,
                                                int* __restrict__ bsum) {
    __shared__ int ws[16];
    const int t = threadIdx.x, lane = t & 63, wv = t >> 6;
    const int base = blockIdx.x * SC_ELE;
    const int e0 = base + 2 * t, e1 = e0 + 1;
    const int v0 = (e0 < NN) ? deg[e0] : 0;
    const int v1 = (e1 < NN) ? deg[e1] : 0;
    const int s = v0 + v1;
    int incl = s;
    #pragma unroll
    for (int o = 1; o < 64; o <<= 1) {
        int u = __shfl_up(incl, o);
        if (lane >= o) incl += u;
    }
    if (lane == 63) ws[wv] = incl;
    __syncthreads();
    if (wv == 0) {
        int x = (lane < 16) ? ws[lane] : 0;
        int ix = x;
        #pragma unroll
        for (int o = 1; o < 16; o <<= 1) {
            int u = __shfl_up(ix, o);
            if (lane >= o) ix += u;
        }
        if (lane < 16) ws[lane] = ix - x;          // exclusive wave offsets
        if (lane == 15) bsum[blockIdx.x] = ix;     // block total
    }
    __syncthreads();
    const int excl = incl - s + ws[wv];
    if (e0 < NN) part[e0] = excl;
    if (e1 < NN) part[e1] = excl + v0;
}

// ------------------------------------------- hierarchical scan, pass 2 ----
__global__ void k_scan2(const int* __restrict__ bsum, int* __restrict__ boff) {
    const int lane = threadIdx.x;                   // 64 threads, 1 block
    const int v = (lane < NSCAN) ? bsum[lane] : 0;
    int ix = v;
    #pragma unroll
    for (int o = 1; o < 64; o <<= 1) {
        int u = __shfl_up(ix, o);
        if (lane >= o) ix += u;
    }
    if (lane < NSCAN) boff[lane] = ix - v;
}

// --------------------------- hierarchical scan, pass 3 (+cur, +off[NN]) ----
__global__ void k_scan3(const int* __restrict__ part, const int* __restrict__ boff,
                        int* __restrict__ off, int* __restrict__ cur) {
    int i = blockIdx.x * 256 + threadIdx.x;
    if (i < NN) {
        int o = part[i] + boff[i >> 11];
        off[i] = o;
        cur[i] = o;
        if (i == 0) off[NN] = NE;
    }
}

// ------------------------------------------------------------ csr fill ----
__global__ void k_fill(const int* __restrict__ src, const int* __restrict__ dst,
                       int* __restrict__ cur, int* __restrict__ csr) {
    int e = blockIdx.x * 256 + threadIdx.x;
    if (e < NE) {
        int p = atomicAdd(&cur[dst[e]], 1);
        csr[p] = src[e];
    }
}

// ---------------- aggregate: a = f(h) + sum_in f(h), f = norm+relu ------
// NORM=0: f = identity. NORM=1: f(v)=relu(v*sc+sh), (sc,sh) recomputed per
// lane from prev layer's stats. One wave per node; lane owns cols 2l,2l+1.
// Unroll-4: four independent row loads in flight per iteration.
template <int NORM>
__global__ __launch_bounds__(256) void k_agg(const float* __restrict__ h,
                                             const float* __restrict__ bnsum,
                                             const float* __restrict__ bnsq,
                                             const float* __restrict__ gamma,
                                             const float* __restrict__ beta,
                                             const int* __restrict__ off,
                                             const int* __restrict__ csr,
                                             float* __restrict__ a) {
    int wid  = (blockIdx.x * 256 + threadIdx.x) >> 6;
    int lane = threadIdx.x & 63;
    if (wid >= NN) return;

    float2 scv = make_float2(1.f, 0.f), shv = make_float2(0.f, 0.f);
    if (NORM) {
        const int j0 = lane * 2;
        const float invN = 1.0f / (float)NN;
        float mu0 = bnsum[j0] * invN;
        float mu1 = bnsum[j0 + 1] * invN;
        float k0 = rsqrtf(bnsq[j0] * invN - mu0 * mu0 + BN_EPS) * gamma[j0];
        float k1 = rsqrtf(bnsq[j0 + 1] * invN - mu1 * mu1 + BN_EPS) * gamma[j0 + 1];
        scv = make_float2(k0, k1);
        shv = make_float2(beta[j0] - mu0 * k0, beta[j0 + 1] - mu1 * k1);
    }

    const int start = off[wid], end = off[wid + 1];
    float2 v = *(const float2*)&h[(size_t)wid * DIM + lane * 2];
    float2 acc;
    if (NORM) {
        acc.x = fmaxf(fmaf(v.x, scv.x, shv.x), 0.f);
        acc.y = fmaxf(fmaf(v.y, scv.y, shv.y), 0.f);
    } else {
        acc = v;
    }
    int i = start;
    for (; i + 3 < end; i += 4) {           // 4 independent loads in flight
        int s0 = csr[i], s1 = csr[i + 1], s2 = csr[i + 2], s3 = csr[i + 3];
        float2 v0 = *(const float2*)&h[(size_t)s0 * DIM + lane * 2];
        float2 v1 = *(const float2*)&h[(size_t)s1 * DIM + lane * 2];
        float2 v2 = *(const float2*)&h[(size_t)s2 * DIM + lane * 2];
        float2 v3 = *(const float2*)&h[(size_t)s3 * DIM + lane * 2];
        if (NORM) {
            v0.x = fmaxf(fmaf(v0.x, scv.x, shv.x), 0.f);
            v0.y = fmaxf(fmaf(v0.y, scv.y, shv.y), 0.f);
            v1.x = fmaxf(fmaf(v1.x, scv.x, shv.x), 0.f);
            v1.y = fmaxf(fmaf(v1.y, scv.y, shv.y), 0.f);
            v2.x = fmaxf(fmaf(v2.x, scv.x, shv.x), 0.f);
            v2.y = fmaxf(fmaf(v2.y, scv.y, shv.y), 0.f);
            v3.x = fmaxf(fmaf(v3.x, scv.x, shv.x), 0.f);
            v3.y = fmaxf(fmaf(v3.y, scv.y, shv.y), 0.f);
        }
        acc.x += v0.x + v1.x + v2.x + v3.x;
        acc.y += v0.y + v1.y + v2.y + v3.y;
    }
    for (; i < end; ++i) {
        int s0 = csr[i];
        float2 v0 = *(const float2*)&h[(size_t)s0 * DIM + lane * 2];
        if (NORM) {
            v0.x = fmaxf(fmaf(v0.x, scv.x, shv.x), 0.f);
            v0.y = fmaxf(fmaf(v0.y, scv.y, shv.y), 0.f);
        }
        acc.x += v0.x;
        acc.y += v0.y;
    }
    *(float2*)&a[(size_t)wid * DIM + lane * 2] = acc;
}

// ------------------------------------------- k_mlp helpers --------------
__device__ __forceinline__ void stage_w(float (*__restrict__ wb)[DIM],
                                        const float* __restrict__ W, int t) {
    // stage KH x DIM floats (32 KB): 8 float4 per thread, coalesced
    #pragma unroll
    for (int i = 0; i < 8; ++i) {
        int f4 = t + i * 256;
        int kk = f4 >> 5, j4 = f4 & 31;
        *(float4*)&wb[kk][j4 * 4] = *(const float4*)&W[kk * DIM + j4 * 4];
    }
}

__device__ __forceinline__ void gemm_half(const float (*__restrict__ zt)[DIM],
                                          const float (*__restrict__ wb)[DIM],
                                          int r, int c, int hbase,
                                          float acc[4][4]) {
    for (int k = 0; k < KH; k += 4) {
        float4 a4[4];
        #pragma unroll
        for (int i = 0; i < 4; ++i) a4[i] = *(const float4*)&zt[r * 4 + i][hbase + k];
        #pragma unroll
        for (int kk = 0; kk < 4; ++kk) {
            const float4 b = *(const float4*)&wb[k + kk][c * 4];
            #pragma unroll
            for (int i = 0; i < 4; ++i) {
                const float a = (&a4[i].x)[kk];
                acc[i][0] = fmaf(a, b.x, acc[i][0]);
                acc[i][1] = fmaf(a, b.y, acc[i][1]);
                acc[i][2] = fmaf(a, b.z, acc[i][2]);
                acc[i][3] = fmaf(a, b.w, acc[i][3]);
            }
        }
    }
}

// -------------------- MLP in-place: z = relu(zW1+b1)W2+b2, + BN stats ----
// W staged in LDS in two 32 KB K-halves -> 48 KB total LDS -> 3 blocks/CU.
// Accumulation order over K identical to a monolithic K loop (bit-exact).
__global__ __launch_bounds__(256, 3) void k_mlp(float* __restrict__ z,
                                                const float* __restrict__ W1,
                                                const float* __restrict__ b1,
                                                const float* __restrict__ W2,
                                                const float* __restrict__ b2,
                                                float* __restrict__ bnsum,
                                                float* __restrict__ bnsq) {
    __shared__ float zt[TM][DIM];   // 16 KB: A tile -> y1 tile -> stats scratch
    __shared__ float wb[KH][DIM];   // 32 KB: W K-half buffer
    const int t = threadIdx.x;
    const int c = t & 31;           // output cols 4c..4c+3
    const int r = t >> 5;           // row group: rows 4r..4r+3
    const int row0 = blockIdx.x * TM;

    // ---- load z tile + stage W1 rows 0..63 ----
    #pragma unroll
    for (int i = 0; i < 4; ++i) {
        int f4 = t + i * 256;
        int rr = f4 >> 5, c4 = f4 & 31;
        int g  = row0 + rr;
        float4 v = make_float4(0.f, 0.f, 0.f, 0.f);
        if (g < NN) v = *(const float4*)&z[(size_t)g * DIM + c4 * 4];
        *(float4*)&zt[rr][c4 * 4] = v;
    }
    stage_w(wb, W1, t);
    __syncthreads();

    // ---- GEMM1 ----
    float acc[4][4];
    #pragma unroll
    for (int i = 0; i < 4; ++i)
        #pragma unroll
        for (int j = 0; j < 4; ++j) acc[i][j] = 0.0f;

    gemm_half(zt, wb, r, c, 0, acc);
    __syncthreads();                         // wb reads done
    stage_w(wb, W1 + KH * DIM, t);           // W1 rows 64..127
    __syncthreads();
    gemm_half(zt, wb, r, c, KH, acc);
    __syncthreads();                         // zt reads done (pre-overwrite)

    // ---- bias1 + relu -> y1 into zt; stage W2 rows 0..63 ----
    const float4 bias1 = *(const float4*)&b1[c * 4];
    #pragma unroll
    for (int i = 0; i < 4; ++i) {
        float4 y;
        y.x = fmaxf(acc[i][0] + bias1.x, 0.f);
        y.y = fmaxf(acc[i][1] + bias1.y, 0.f);
        y.z = fmaxf(acc[i][2] + bias1.z, 0.f);
        y.w = fmaxf(acc[i][3] + bias1.w, 0.f);
        *(float4*)&zt[r * 4 + i][c * 4] = y;
    }
    stage_w(wb, W2, t);
    __syncthreads();

    // ---- GEMM2 ----
    #pragma unroll
    for (int i = 0; i < 4; ++i)
        #pragma unroll
        for (int j = 0; j < 4; ++j) acc[i][j] = 0.0f;

    gemm_half(zt, wb, r, c, 0, acc);
    __syncthreads();                         // wb reads done
    stage_w(wb, W2 + KH * DIM, t);           // W2 rows 64..127
    __syncthreads();
    gemm_half(zt, wb, r, c, KH, acc);
    __syncthreads();                         // zt reads done (pre-scratch)

    // ---- bias2, write z (pre-BN) in place, block stats -> atomics ----
    const float4 bias2 = *(const float4*)&b2[c * 4];
    float s[4] = {0.f, 0.f, 0.f, 0.f};
    float q[4] = {0.f, 0.f, 0.f, 0.f};
    #pragma unroll
    for (int i = 0; i < 4; ++i) {
        int g = row0 + r * 4 + i;
        float4 zv;
        zv.x = acc[i][0] + bias2.x;
        zv.y = acc[i][1] + bias2.y;
        zv.z = acc[i][2] + bias2.z;
        zv.w = acc[i][3] + bias2.w;
        if (g < NN) {
            *(float4*)&z[(size_t)g * DIM + c * 4] = zv;
            s[0] += zv.x; s[1] += zv.y; s[2] += zv.z; s[3] += zv.w;
            q[0] += zv.x * zv.x; q[1] += zv.y * zv.y;
            q[2] += zv.z * zv.z; q[3] += zv.w * zv.w;
        }
    }
    float* scratch = &zt[0][0];     // [0:1024)=sum, [1024:2048)=sq
    #pragma unroll
    for (int j = 0; j < 4; ++j) {
        scratch[r * DIM + c * 4 + j]        = s[j];
        scratch[1024 + r * DIM + c * 4 + j] = q[j];
    }
    __syncthreads();
    if (t < DIM) {
        float ss = 0.f, qq = 0.f;
        #pragma unroll
        for (int rr = 0; rr < 8; ++rr) {
            ss += scratch[rr * DIM + t];
            qq += scratch[1024 + rr * DIM + t];
        }
        atomicAdd(&bnsum[t], ss);
        atomicAdd(&bnsq[t], qq);
    }
}

// ------------- final FC with fused last-layer norm (per-lane sc/sh) ----
__global__ __launch_bounds__(256) void k_fc(const float* __restrict__ z,
                                            const float* __restrict__ bnsum,
                                            const float* __restrict__ bnsq,
                                            const float* __restrict__ gamma,
                                            const float* __restrict__ beta,
                                            const float* __restrict__ fc_w,
                                            const float* __restrict__ fc_b,
                                            float* __restrict__ out) {
    int wid  = (blockIdx.x * 256 + threadIdx.x) >> 6;
    int lane = threadIdx.x & 63;
    if (wid >= NN) return;
    const int j0 = lane * 2;
    const float invN = 1.0f / (float)NN;
    float mu0 = bnsum[j0] * invN;
    float mu1 = bnsum[j0 + 1] * invN;
    float k0 = rsqrtf(bnsq[j0] * invN - mu0 * mu0 + BN_EPS) * gamma[j0];
    float k1 = rsqrtf(bnsq[j0 + 1] * invN - mu1 * mu1 + BN_EPS) * gamma[j0 + 1];
    float sh0 = beta[j0] - mu0 * k0;
    float sh1 = beta[j0 + 1] - mu1 * k1;

    float2 v = *(const float2*)&z[(size_t)wid * DIM + lane * 2];
    v.x = fmaxf(fmaf(v.x, k0, sh0), 0.f);
    v.y = fmaxf(fmaf(v.y, k1, sh1), 0.f);
    float2 wv = *(const float2*)&fc_w[lane * 2];
    float s = v.x * wv.x + v.y * wv.y;
    #pragma unroll
    for (int o = 32; o >= 1; o >>= 1) s += __shfl_down(s, o);
    if (lane == 0) out[wid] = s + fc_b[0];
}

// -------------------------------------------------------------- launch ----
extern "C" void kernel_launch(void* const* d_in, const int* in_sizes, int n_in,
                              void* d_out, int out_size, void* d_ws, size_t ws_size,
                              hipStream_t stream) {
    const float* x     = (const float*)d_in[0];
    const int*   src   = (const int*)d_in[1];          // edge_index[0]
    const int*   dst   = ((const int*)d_in[1]) + NE;   // edge_index[1]
    const float* W1    = (const float*)d_in[2];
    const float* b1    = (const float*)d_in[3];
    const float* W2    = (const float*)d_in[4];
    const float* b2    = (const float*)d_in[5];
    const float* gamma = (const float*)d_in[6];
    const float* beta  = (const float*)d_in[7];
    const float* fc_w  = (const float*)d_in[8];
    const float* fc_b  = (const float*)d_in[9];
    float* out = (float*)d_out;

    // workspace carve (16B aligned chunks)
    char* ws = (char*)d_ws;
    size_t o = 0;
    auto carve = [&](size_t bytes) {
        char* p = ws + o;
        o += (bytes + 15) & ~(size_t)15;
        return p;
    };
    int*   deg     = (int*)carve(NN * 4);
    int*   off     = (int*)carve((NN + 1) * 4);
    int*   cur     = (int*)carve(NN * 4);
    int*   csr     = (int*)carve(NE * 4);
    int*   part    = (int*)carve(NN * 4);
    int*   bsum    = (int*)carve(NSCAN * 4);
    int*   boff    = (int*)carve(NSCAN * 4);
    float* bnstats = (float*)carve(LAYERS * 2 * DIM * 4);  // [sum(3x128) | sq(3x128)]
    float* zA      = (float*)carve((size_t)NN * DIM * 4);
    float* zB      = (float*)carve((size_t)NN * DIM * 4);

    // ---- CSR build (once per call) ----
    k_init<<<(NN + 255) / 256, 256, 0, stream>>>(deg, bnstats);
    k_hist<<<(NE + 255) / 256, 256, 0, stream>>>(dst, deg);
    k_scan1<<<NSCAN, 1024, 0, stream>>>(deg, part, bsum);
    k_scan2<<<1, 64, 0, stream>>>(bsum, boff);
    k_scan3<<<(NN + 255) / 256, 256, 0, stream>>>(part, boff, off, cur);
    k_fill<<<(NE + 255) / 256, 256, 0, stream>>>(src, dst, cur, csr);

    // ---- layers: agg(norm-fused) -> mlp(in-place) ----
    const int nblk_mlp = (NN + TM - 1) / TM;
    const int nblk_agg = (NN * 64 + 255) / 256;
    float* zbuf[2] = {zA, zB};
    for (int l = 0; l < LAYERS; ++l) {
        const float* hin = (l == 0) ? x : zbuf[(l + 1) & 1];
        float* zo = zbuf[l & 1];
        float* sum_l = bnstats + l * DIM;
        float* sq_l  = bnstats + LAYERS * DIM + l * DIM;
        const float* sum_p = bnstats + (l - 1) * DIM;
        const float* sq_p  = bnstats + LAYERS * DIM + (l - 1) * DIM;
        if (l == 0)
            k_agg<0><<<nblk_agg, 256, 0, stream>>>(hin, nullptr, nullptr, nullptr,
                                                   nullptr, off, csr, zo);
        else
            k_agg<1><<<nblk_agg, 256, 0, stream>>>(hin, sum_p, sq_p,
                                                   gamma + (l - 1) * DIM,
                                                   beta + (l - 1) * DIM,
                                                   off, csr, zo);
        k_mlp<<<nblk_mlp, 256, 0, stream>>>(zo,
                                            W1 + (size_t)l * DIM * DIM, b1 + l * DIM,
                                            W2 + (size_t)l * DIM * DIM, b2 + l * DIM,
                                            sum_l, sq_l);
    }

    // ---- final FC (fused last norm) ----
    k_fc<<<(NN * 64 + 255) / 256, 256, 0, stream>>>(zbuf[(LAYERS + 1) & 1],
                                                    bnstats + (LAYERS - 1) * DIM,
                                                    bnstats + (2 * LAYERS - 1) * DIM,
                                                    gamma + (LAYERS - 1) * DIM,
                                                    beta + (LAYERS - 1) * DIM,
                                                    fc_w, fc_b, out);
}

// Round 8
// 4386.938 us; speedup vs baseline: 1.0054x; 1.0054x over previous
//
#include <hip/hip_runtime.h>
#include <math.h>

#define NN 50000
#define NE 600000
#define DIM 128
#define LAYERS 3
#define BN_EPS 1e-5f

#define SC_ELE 2048
#define NSCAN ((NN + SC_ELE - 1) / SC_ELE)   // 25 scan blocks
#define TM 32
#define KH 64                                 // K-half staged in LDS

// ---------------------------------------------------------------- init ----
__global__ void k_init(int* __restrict__ deg, float* __restrict__ bnstats) {
    int i = blockIdx.x * 256 + threadIdx.x;
    if (i < NN) deg[i] = 0;
    if (i < LAYERS * 2 * DIM) bnstats[i] = 0.0f;
}

// ----------------------------------------------------------- histogram ----
__global__ void k_hist(const int* __restrict__ dst, int* __restrict__ deg) {
    int e = blockIdx.x * 256 + threadIdx.x;
    if (e < NE) atomicAdd(&deg[dst[e]], 1);
}

// ------------------------------------------- hierarchical scan, pass 1 ----
__global__ __launch_bounds__(1024) void k_scan1(const int* __restrict__ deg,
                                                int* __restrict__ part,
                                                int* __restrict__ bsum) {
    __shared__ int ws[16];
    const int t = threadIdx.x, lane = t & 63, wv = t >> 6;
    const int base = blockIdx.x * SC_ELE;
    const int e0 = base + 2 * t, e1 = e0 + 1;
    const int v0 = (e0 < NN) ? deg[e0] : 0;
    const int v1 = (e1 < NN) ? deg[e1] : 0;
    const int s = v0 + v1;
    int incl = s;
    #pragma unroll
    for (int o = 1; o < 64; o <<= 1) {
        int u = __shfl_up(incl, o);
        if (lane >= o) incl += u;
    }
    if (lane == 63) ws[wv] = incl;
    __syncthreads();
    if (wv == 0) {
        int x = (lane < 16) ? ws[lane] : 0;
        int ix = x;
        #pragma unroll
        for (int o = 1; o < 16; o <<= 1) {
            int u = __shfl_up(ix, o);
            if (lane >= o) ix += u;
        }
        if (lane < 16) ws[lane] = ix - x;          // exclusive wave offsets
        if (lane == 15) bsum[blockIdx.x] = ix;     // block total
    }
    __syncthreads();
    const int excl = incl - s + ws[wv];
    if (e0 < NN) part[e0] = excl;
    if (e1 < NN) part[e1] = excl + v0;
}

// ------------------------------------------- hierarchical scan, pass 2 ----
__global__ void k_scan2(const int* __restrict__ bsum, int* __restrict__ boff) {
    const int lane = threadIdx.x;                   // 64 threads, 1 block
    const int v = (lane < NSCAN) ? bsum[lane] : 0;
    int ix = v;
    #pragma unroll
    for (int o = 1; o < 64; o <<= 1) {
        int u = __shfl_up(ix, o);
        if (lane >= o) ix += u;
    }
    if (lane < NSCAN) boff[lane] = ix - v;
}

// --------------------------- hierarchical scan, pass 3 (+cur, +off[NN]) ----
__global__ void k_scan3(const int* __restrict__ part, const int* __restrict__ boff,
                        int* __restrict__ off, int* __restrict__ cur) {
    int i = blockIdx.x * 256 + threadIdx.x;
    if (i < NN) {
        int o = part[i] + boff[i >> 11];
        off[i] = o;
        cur[i] = o;
        if (i == 0) off[NN] = NE;
    }
}

// ------------------------------------------------------------ csr fill ----
__global__ void k_fill(const int* __restrict__ src, const int* __restrict__ dst,
                       int* __restrict__ cur, int* __restrict__ csr) {
    int e = blockIdx.x * 256 + threadIdx.x;
    if (e < NE) {
        int p = atomicAdd(&cur[dst[e]], 1);
        csr[p] = src[e];
    }
}

// ---------------- aggregate: a = f(h) + sum_in f(h), f = norm+relu ------
// NORM=0: f = identity. NORM=1: f(v)=relu(v*sc+sh), (sc,sh) recomputed per
// lane from prev layer's stats. One wave per node; lane owns cols 2l,2l+1.
// Unroll-4: four independent row loads in flight per iteration.
template <int NORM>
__global__ __launch_bounds__(256) void k_agg(const float* __restrict__ h,
                                             const float* __restrict__ bnsum,
                                             const float* __restrict__ bnsq,
                                             const float* __restrict__ gamma,
                                             const float* __restrict__ beta,
                                             const int* __restrict__ off,
                                             const int* __restrict__ csr,
                                             float* __restrict__ a) {
    int wid  = (blockIdx.x * 256 + threadIdx.x) >> 6;
    int lane = threadIdx.x & 63;
    if (wid >= NN) return;

    float2 scv = make_float2(1.f, 0.f), shv = make_float2(0.f, 0.f);
    if (NORM) {
        const int j0 = lane * 2;
        const float invN = 1.0f / (float)NN;
        float mu0 = bnsum[j0] * invN;
        float mu1 = bnsum[j0 + 1] * invN;
        float k0 = rsqrtf(bnsq[j0] * invN - mu0 * mu0 + BN_EPS) * gamma[j0];
        float k1 = rsqrtf(bnsq[j0 + 1] * invN - mu1 * mu1 + BN_EPS) * gamma[j0 + 1];
        scv = make_float2(k0, k1);
        shv = make_float2(beta[j0] - mu0 * k0, beta[j0 + 1] - mu1 * k1);
    }

    const int start = off[wid], end = off[wid + 1];
    float2 v = *(const float2*)&h[(size_t)wid * DIM + lane * 2];
    float2 acc;
    if (NORM) {
        acc.x = fmaxf(fmaf(v.x, scv.x, shv.x), 0.f);
        acc.y = fmaxf(fmaf(v.y, scv.y, shv.y), 0.f);
    } else {
        acc = v;
    }
    int i = start;
    for (; i + 3 < end; i += 4) {           // 4 independent loads in flight
        int s0 = csr[i], s1 = csr[i + 1], s2 = csr[i + 2], s3 = csr[i + 3];
        float2 v0 = *(const float2*)&h[(size_t)s0 * DIM + lane * 2];
        float2 v1 = *(const float2*)&h[(size_t)s1 * DIM + lane * 2];
        float2 v2 = *(const float2*)&h[(size_t)s2 * DIM + lane * 2];
        float2 v3 = *(const float2*)&h[(size_t)s3 * DIM + lane * 2];
        if (NORM) {
            v0.x = fmaxf(fmaf(v0.x, scv.x, shv.x), 0.f);
            v0.y = fmaxf(fmaf(v0.y, scv.y, shv.y), 0.f);
            v1.x = fmaxf(fmaf(v1.x, scv.x, shv.x), 0.f);
            v1.y = fmaxf(fmaf(v1.y, scv.y, shv.y), 0.f);
            v2.x = fmaxf(fmaf(v2.x, scv.x, shv.x), 0.f);
            v2.y = fmaxf(fmaf(v2.y, scv.y, shv.y), 0.f);
            v3.x = fmaxf(fmaf(v3.x, scv.x, shv.x), 0.f);
            v3.y = fmaxf(fmaf(v3.y, scv.y, shv.y), 0.f);
        }
        acc.x += v0.x + v1.x + v2.x + v3.x;
        acc.y += v0.y + v1.y + v2.y + v3.y;
    }
    for (; i < end; ++i) {
        int s0 = csr[i];
        float2 v0 = *(const float2*)&h[(size_t)s0 * DIM + lane * 2];
        if (NORM) {
            v0.x = fmaxf(fmaf(v0.x, scv.x, shv.x), 0.f);
            v0.y = fmaxf(fmaf(v0.y, scv.y, shv.y), 0.f);
        }
        acc.x += v0.x;
        acc.y += v0.y;
    }
    *(float2*)&a[(size_t)wid * DIM + lane * 2] = acc;
}

// ------------------------------------------- k_mlp helpers --------------
__device__ __forceinline__ void stage_w(float (*__restrict__ wb)[DIM],
                                        const float* __restrict__ W, int t) {
    // stage KH x DIM floats (32 KB): 8 float4 per thread, coalesced
    #pragma unroll
    for (int i = 0; i < 8; ++i) {
        int f4 = t + i * 256;
        int kk = f4 >> 5, j4 = f4 & 31;
        *(float4*)&wb[kk][j4 * 4] = *(const float4*)&W[kk * DIM + j4 * 4];
    }
}

__device__ __forceinline__ void gemm_half(const float (*__restrict__ zt)[DIM],
                                          const float (*__restrict__ wb)[DIM],
                                          int r, int c, int hbase,
                                          float acc[4][4]) {
    for (int k = 0; k < KH; k += 4) {
        float4 a4[4];
        #pragma unroll
        for (int i = 0; i < 4; ++i) a4[i] = *(const float4*)&zt[r * 4 + i][hbase + k];
        #pragma unroll
        for (int kk = 0; kk < 4; ++kk) {
            const float4 b = *(const float4*)&wb[k + kk][c * 4];
            #pragma unroll
            for (int i = 0; i < 4; ++i) {
                const float a = (&a4[i].x)[kk];
                acc[i][0] = fmaf(a, b.x, acc[i][0]);
                acc[i][1] = fmaf(a, b.y, acc[i][1]);
                acc[i][2] = fmaf(a, b.z, acc[i][2]);
                acc[i][3] = fmaf(a, b.w, acc[i][3]);
            }
        }
    }
}

// -------------------- MLP in-place: z = relu(zW1+b1)W2+b2, + BN stats ----
// W staged in LDS in two 32 KB K-halves -> 48 KB total LDS -> 3 blocks/CU.
// Accumulation order over K identical to a monolithic K loop (bit-exact).
__global__ __launch_bounds__(256, 3) void k_mlp(float* __restrict__ z,
                                                const float* __restrict__ W1,
                                                const float* __restrict__ b1,
                                                const float* __restrict__ W2,
                                                const float* __restrict__ b2,
                                                float* __restrict__ bnsum,
                                                float* __restrict__ bnsq) {
    __shared__ float zt[TM][DIM];   // 16 KB: A tile -> y1 tile -> stats scratch
    __shared__ float wb[KH][DIM];   // 32 KB: W K-half buffer
    const int t = threadIdx.x;
    const int c = t & 31;           // output cols 4c..4c+3
    const int r = t >> 5;           // row group: rows 4r..4r+3
    const int row0 = blockIdx.x * TM;

    // ---- load z tile + stage W1 rows 0..63 ----
    #pragma unroll
    for (int i = 0; i < 4; ++i) {
        int f4 = t + i * 256;
        int rr = f4 >> 5, c4 = f4 & 31;
        int g  = row0 + rr;
        float4 v = make_float4(0.f, 0.f, 0.f, 0.f);
        if (g < NN) v = *(const float4*)&z[(size_t)g * DIM + c4 * 4];
        *(float4*)&zt[rr][c4 * 4] = v;
    }
    stage_w(wb, W1, t);
    __syncthreads();

    // ---- GEMM1 ----
    float acc[4][4];
    #pragma unroll
    for (int i = 0; i < 4; ++i)
        #pragma unroll
        for (int j = 0; j < 4; ++j) acc[i][j] = 0.0f;

    gemm_half(zt, wb, r, c, 0, acc);
    __syncthreads();                         // wb reads done
    stage_w(wb, W1 + KH * DIM, t);           // W1 rows 64..127
    __syncthreads();
    gemm_half(zt, wb, r, c, KH, acc);
    __syncthreads();                         // zt reads done (pre-overwrite)

    // ---- bias1 + relu -> y1 into zt; stage W2 rows 0..63 ----
    const float4 bias1 = *(const float4*)&b1[c * 4];
    #pragma unroll
    for (int i = 0; i < 4; ++i) {
        float4 y;
        y.x = fmaxf(acc[i][0] + bias1.x, 0.f);
        y.y = fmaxf(acc[i][1] + bias1.y, 0.f);
        y.z = fmaxf(acc[i][2] + bias1.z, 0.f);
        y.w = fmaxf(acc[i][3] + bias1.w, 0.f);
        *(float4*)&zt[r * 4 + i][c * 4] = y;
    }
    stage_w(wb, W2, t);
    __syncthreads();

    // ---- GEMM2 ----
    #pragma unroll
    for (int i = 0; i < 4; ++i)
        #pragma unroll
        for (int j = 0; j < 4; ++j) acc[i][j] = 0.0f;

    gemm_half(zt, wb, r, c, 0, acc);
    __syncthreads();                         // wb reads done
    stage_w(wb, W2 + KH * DIM, t);           // W2 rows 64..127
    __syncthreads();
    gemm_half(zt, wb, r, c, KH, acc);
    __syncthreads();                         // zt reads done (pre-scratch)

    // ---- bias2, write z (pre-BN) in place, block stats -> atomics ----
    const float4 bias2 = *(const float4*)&b2[c * 4];
    float s[4] = {0.f, 0.f, 0.f, 0.f};
    float q[4] = {0.f, 0.f, 0.f, 0.f};
    #pragma unroll
    for (int i = 0; i < 4; ++i) {
        int g = row0 + r * 4 + i;
        float4 zv;
        zv.x = acc[i][0] + bias2.x;
        zv.y = acc[i][1] + bias2.y;
        zv.z = acc[i][2] + bias2.z;
        zv.w = acc[i][3] + bias2.w;
        if (g < NN) {
            *(float4*)&z[(size_t)g * DIM + c * 4] = zv;
            s[0] += zv.x; s[1] += zv.y; s[2] += zv.z; s[3] += zv.w;
            q[0] += zv.x * zv.x; q[1] += zv.y * zv.y;
            q[2] += zv.z * zv.z; q[3] += zv.w * zv.w;
        }
    }
    float* scratch = &zt[0][0];     // [0:1024)=sum, [1024:2048)=sq
    #pragma unroll
    for (int j = 0; j < 4; ++j) {
        scratch[r * DIM + c * 4 + j]        = s[j];
        scratch[1024 + r * DIM + c * 4 + j] = q[j];
    }
    __syncthreads();
    if (t < DIM) {
        float ss = 0.f, qq = 0.f;
        #pragma unroll
        for (int rr = 0; rr < 8; ++rr) {
            ss += scratch[rr * DIM + t];
            qq += scratch[1024 + rr * DIM + t];
        }
        atomicAdd(&bnsum[t], ss);
        atomicAdd(&bnsq[t], qq);
    }
}

// ------------- final FC with fused last-layer norm (per-lane sc/sh) ----
__global__ __launch_bounds__(256) void k_fc(const float* __restrict__ z,
                                            const float* __restrict__ bnsum,
                                            const float* __restrict__ bnsq,
                                            const float* __restrict__ gamma,
                                            const float* __restrict__ beta,
                                            const float* __restrict__ fc_w,
                                            const float* __restrict__ fc_b,
                                            float* __restrict__ out) {
    int wid  = (blockIdx.x * 256 + threadIdx.x) >> 6;
    int lane = threadIdx.x & 63;
    if (wid >= NN) return;
    const int j0 = lane * 2;
    const float invN = 1.0f / (float)NN;
    float mu0 = bnsum[j0] * invN;
    float mu1 = bnsum[j0 + 1] * invN;
    float k0 = rsqrtf(bnsq[j0] * invN - mu0 * mu0 + BN_EPS) * gamma[j0];
    float k1 = rsqrtf(bnsq[j0 + 1] * invN - mu1 * mu1 + BN_EPS) * gamma[j0 + 1];
    float sh0 = beta[j0] - mu0 * k0;
    float sh1 = beta[j0 + 1] - mu1 * k1;

    float2 v = *(const float2*)&z[(size_t)wid * DIM + lane * 2];
    v.x = fmaxf(fmaf(v.x, k0, sh0), 0.f);
    v.y = fmaxf(fmaf(v.y, k1, sh1), 0.f);
    float2 wv = *(const float2*)&fc_w[lane * 2];
    float s = v.x * wv.x + v.y * wv.y;
    #pragma unroll
    for (int o = 32; o >= 1; o >>= 1) s += __shfl_down(s, o);
    if (lane == 0) out[wid] = s + fc_b[0];
}

// -------------------------------------------------------------- launch ----
extern "C" void kernel_launch(void* const* d_in, const int* in_sizes, int n_in,
                              void* d_out, int out_size, void* d_ws, size_t ws_size,
                              hipStream_t stream) {
    const float* x     = (const float*)d_in[0];
    const int*   src   = (const int*)d_in[1];          // edge_index[0]
    const int*   dst   = ((const int*)d_in[1]) + NE;   // edge_index[1]
    const float* W1    = (const float*)d_in[2];
    const float* b1    = (const float*)d_in[3];
    const float* W2    = (const float*)d_in[4];
    const float* b2    = (const float*)d_in[5];
    const float* gamma = (const float*)d_in[6];
    const float* beta  = (const float*)d_in[7];
    const float* fc_w  = (const float*)d_in[8];
    const float* fc_b  = (const float*)d_in[9];
    float* out = (float*)d_out;

    // workspace carve (16B aligned chunks)
    char* ws = (char*)d_ws;
    size_t o = 0;
    auto carve = [&](size_t bytes) {
        char* p = ws + o;
        o += (bytes + 15) & ~(size_t)15;
        return p;
    };
    int*   deg     = (int*)carve(NN * 4);
    int*   off     = (int*)carve((NN + 1) * 4);
    int*   cur     = (int*)carve(NN * 4);
    int*   csr     = (int*)carve(NE * 4);
    int*   part    = (int*)carve(NN * 4);
    int*   bsum    = (int*)carve(NSCAN * 4);
    int*   boff    = (int*)carve(NSCAN * 4);
    float* bnstats = (float*)carve(LAYERS * 2 * DIM * 4);  // [sum(3x128) | sq(3x128)]
    float* zA      = (float*)carve((size_t)NN * DIM * 4);
    float* zB      = (float*)carve((size_t)NN * DIM * 4);

    // ---- CSR build (once per call) ----
    k_init<<<(NN + 255) / 256, 256, 0, stream>>>(deg, bnstats);
    k_hist<<<(NE + 255) / 256, 256, 0, stream>>>(dst, deg);
    k_scan1<<<NSCAN, 1024, 0, stream>>>(deg, part, bsum);
    k_scan2<<<1, 64, 0, stream>>>(bsum, boff);
    k_scan3<<<(NN + 255) / 256, 256, 0, stream>>>(part, boff, off, cur);
    k_fill<<<(NE + 255) / 256, 256, 0, stream>>>(src, dst, cur, csr);

    // ---- layers: agg(norm-fused) -> mlp(in-place) ----
    const int nblk_mlp = (NN + TM - 1) / TM;
    const int nblk_agg = (NN * 64 + 255) / 256;
    float* zbuf[2] = {zA, zB};
    for (int l = 0; l < LAYERS; ++l) {
        const float* hin = (l == 0) ? x : zbuf[(l + 1) & 1];
        float* zo = zbuf[l & 1];
        float* sum_l = bnstats + l * DIM;
        float* sq_l  = bnstats + LAYERS * DIM + l * DIM;
        const float* sum_p = bnstats + (l - 1) * DIM;
        const float* sq_p  = bnstats + LAYERS * DIM + (l - 1) * DIM;
        if (l == 0)
            k_agg<0><<<nblk_agg, 256, 0, stream>>>(hin, nullptr, nullptr, nullptr,
                                                   nullptr, off, csr, zo);
        else
            k_agg<1><<<nblk_agg, 256, 0, stream>>>(hin, sum_p, sq_p,
                                                   gamma + (l - 1) * DIM,
                                                   beta + (l - 1) * DIM,
                                                   off, csr, zo);
        k_mlp<<<nblk_mlp, 256, 0, stream>>>(zo,
                                            W1 + (size_t)l * DIM * DIM, b1 + l * DIM,
                                            W2 + (size_t)l * DIM * DIM, b2 + l * DIM,
                                            sum_l, sq_l);
    }

    // ---- final FC (fused last norm) ----
    k_fc<<<(NN * 64 + 255) / 256, 256, 0, stream>>>(zbuf[(LAYERS + 1) & 1],
                                                    bnstats + (LAYERS - 1) * DIM,
                                                    bnstats + (2 * LAYERS - 1) * DIM,
                                                    gamma + (LAYERS - 1) * DIM,
                                                    beta + (LAYERS - 1) * DIM,
                                                    fc_w, fc_b, out);
}

// Round 10
// 536.599 us; speedup vs baseline: 8.2195x; 8.1755x over previous
//
#include <hip/hip_runtime.h>
#include <math.h>

#define NN 50000
#define NE 600000
#define DIM 128
#define LAYERS 3
#define BN_EPS 1e-5f

#define SC_ELE 2048
#define NSCAN ((NN + SC_ELE - 1) / SC_ELE)   // 25 scan blocks
#define TM 32
#define KH 64                                 // K-half staged in LDS

// ---------------------------------------------------------------- init ----
__global__ void k_init(int* __restrict__ deg, float* __restrict__ bnstats) {
    int i = blockIdx.x * 256 + threadIdx.x;
    if (i < NN) deg[i] = 0;
    if (i < LAYERS * 2 * DIM) bnstats[i] = 0.0f;
}

// ----------------------------------------------------------- histogram ----
__global__ void k_hist(const int* __restrict__ dst, int* __restrict__ deg) {
    int e = blockIdx.x * 256 + threadIdx.x;
    if (e < NE) atomicAdd(&deg[dst[e]], 1);
}

// ------------------------------------------- hierarchical scan, pass 1 ----
__global__ __launch_bounds__(1024) void k_scan1(const int* __restrict__ deg,
                                                int* __restrict__ part,
                                                int* __restrict__ bsum) {
    __shared__ int ws[16];
    const int t = threadIdx.x, lane = t & 63, wv = t >> 6;
    const int base = blockIdx.x * SC_ELE;
    const int e0 = base + 2 * t, e1 = e0 + 1;
    const int v0 = (e0 < NN) ? deg[e0] : 0;
    const int v1 = (e1 < NN) ? deg[e1] : 0;
    const int s = v0 + v1;
    int incl = s;
    #pragma unroll
    for (int o = 1; o < 64; o <<= 1) {
        int u = __shfl_up(incl, o);
        if (lane >= o) incl += u;
    }
    if (lane == 63) ws[wv] = incl;
    __syncthreads();
    if (wv == 0) {
        int x = (lane < 16) ? ws[lane] : 0;
        int ix = x;
        #pragma unroll
        for (int o = 1; o < 16; o <<= 1) {
            int u = __shfl_up(ix, o);
            if (lane >= o) ix += u;
        }
        if (lane < 16) ws[lane] = ix - x;          // exclusive wave offsets
        if (lane == 15) bsum[blockIdx.x] = ix;     // block total
    }
    __syncthreads();
    const int excl = incl - s + ws[wv];
    if (e0 < NN) part[e0] = excl;
    if (e1 < NN) part[e1] = excl + v0;
}

// ------------------------------------------- hierarchical scan, pass 2 ----
__global__ void k_scan2(const int* __restrict__ bsum, int* __restrict__ boff) {
    const int lane = threadIdx.x;                   // 64 threads, 1 block
    const int v = (lane < NSCAN) ? bsum[lane] : 0;
    int ix = v;
    #pragma unroll
    for (int o = 1; o < 64; o <<= 1) {
        int u = __shfl_up(ix, o);
        if (lane >= o) ix += u;
    }
    if (lane < NSCAN) boff[lane] = ix - v;
}

// --------------------------- hierarchical scan, pass 3 (+cur, +off[NN]) ----
__global__ void k_scan3(const int* __restrict__ part, const int* __restrict__ boff,
                        int* __restrict__ off, int* __restrict__ cur) {
    int i = blockIdx.x * 256 + threadIdx.x;
    if (i < NN) {
        int o = part[i] + boff[i >> 11];
        off[i] = o;
        cur[i] = o;
        if (i == 0) off[NN] = NE;
    }
}

// ------------------------------------------------------------ csr fill ----
__global__ void k_fill(const int* __restrict__ src, const int* __restrict__ dst,
                       int* __restrict__ cur, int* __restrict__ csr) {
    int e = blockIdx.x * 256 + threadIdx.x;
    if (e < NE) {
        int p = atomicAdd(&cur[dst[e]], 1);
        csr[p] = src[e];
    }
}

// ---------------- aggregate: a = f(h) + sum_in f(h), f = norm+relu ------
// NORM=0: f = identity. NORM=1: f(v)=relu(v*sc+sh), (sc,sh) recomputed per
// lane from prev layer's stats. One wave per node; lane owns cols 2l,2l+1.
template <int NORM>
__global__ __launch_bounds__(256) void k_agg(const float* __restrict__ h,
                                             const float* __restrict__ bnsum,
                                             const float* __restrict__ bnsq,
                                             const float* __restrict__ gamma,
                                             const float* __restrict__ beta,
                                             const int* __restrict__ off,
                                             const int* __restrict__ csr,
                                             float* __restrict__ a) {
    int wid  = (blockIdx.x * 256 + threadIdx.x) >> 6;
    int lane = threadIdx.x & 63;
    if (wid >= NN) return;

    float2 scv = make_float2(1.f, 0.f), shv = make_float2(0.f, 0.f);
    if (NORM) {
        const int j0 = lane * 2;
        const float invN = 1.0f / (float)NN;
        float mu0 = bnsum[j0] * invN;
        float mu1 = bnsum[j0 + 1] * invN;
        float k0 = rsqrtf(bnsq[j0] * invN - mu0 * mu0 + BN_EPS) * gamma[j0];
        float k1 = rsqrtf(bnsq[j0 + 1] * invN - mu1 * mu1 + BN_EPS) * gamma[j0 + 1];
        scv = make_float2(k0, k1);
        shv = make_float2(beta[j0] - mu0 * k0, beta[j0 + 1] - mu1 * k1);
    }

    const int start = off[wid], end = off[wid + 1];
    float2 v = *(const float2*)&h[(size_t)wid * DIM + lane * 2];
    float2 acc;
    if (NORM) {
        acc.x = fmaxf(fmaf(v.x, scv.x, shv.x), 0.f);
        acc.y = fmaxf(fmaf(v.y, scv.y, shv.y), 0.f);
    } else {
        acc = v;
    }
    int i = start;
    for (; i + 3 < end; i += 4) {           // 4 independent loads in flight
        int s0 = csr[i], s1 = csr[i + 1], s2 = csr[i + 2], s3 = csr[i + 3];
        float2 v0 = *(const float2*)&h[(size_t)s0 * DIM + lane * 2];
        float2 v1 = *(const float2*)&h[(size_t)s1 * DIM + lane * 2];
        float2 v2 = *(const float2*)&h[(size_t)s2 * DIM + lane * 2];
        float2 v3 = *(const float2*)&h[(size_t)s3 * DIM + lane * 2];
        if (NORM) {
            v0.x = fmaxf(fmaf(v0.x, scv.x, shv.x), 0.f);
            v0.y = fmaxf(fmaf(v0.y, scv.y, shv.y), 0.f);
            v1.x = fmaxf(fmaf(v1.x, scv.x, shv.x), 0.f);
            v1.y = fmaxf(fmaf(v1.y, scv.y, shv.y), 0.f);
            v2.x = fmaxf(fmaf(v2.x, scv.x, shv.x), 0.f);
            v2.y = fmaxf(fmaf(v2.y, scv.y, shv.y), 0.f);
            v3.x = fmaxf(fmaf(v3.x, scv.x, shv.x), 0.f);
            v3.y = fmaxf(fmaf(v3.y, scv.y, shv.y), 0.f);
        }
        acc.x += v0.x + v1.x + v2.x + v3.x;
        acc.y += v0.y + v1.y + v2.y + v3.y;
    }
    for (; i < end; ++i) {
        int s0 = csr[i];
        float2 v0 = *(const float2*)&h[(size_t)s0 * DIM + lane * 2];
        if (NORM) {
            v0.x = fmaxf(fmaf(v0.x, scv.x, shv.x), 0.f);
            v0.y = fmaxf(fmaf(v0.y, scv.y, shv.y), 0.f);
        }
        acc.x += v0.x;
        acc.y += v0.y;
    }
    *(float2*)&a[(size_t)wid * DIM + lane * 2] = acc;
}

// ---- macros (textual inline: no function boundary, no address-taking) ----
// stage KH x DIM floats (32 KB) of W into wb: 8 float4 per thread, coalesced
#define STAGE_W(WPTR)                                                        \
    {                                                                        \
        _Pragma("unroll")                                                    \
        for (int i_ = 0; i_ < 8; ++i_) {                                     \
            int f4_ = t + i_ * 256;                                          \
            int kk_ = f4_ >> 5, j4_ = f4_ & 31;                              \
            *(float4*)&wb[kk_][j4_ * 4] =                                    \
                *(const float4*)&(WPTR)[kk_ * DIM + j4_ * 4];                \
        }                                                                    \
    }

// one K-half GEMM accumulation: acc[i][j] += zt[r*4+i][KB+k] * wb[k][c*4+j]
// explicit .x/.y/.z/.w use -- no address-taken indexing anywhere
#define GEMM_HALF(KB)                                                        \
    for (int k = 0; k < KH; k += 4) {                                        \
        float4 a0_ = *(const float4*)&zt[r * 4 + 0][(KB) + k];               \
        float4 a1_ = *(const float4*)&zt[r * 4 + 1][(KB) + k];               \
        float4 a2_ = *(const float4*)&zt[r * 4 + 2][(KB) + k];               \
        float4 a3_ = *(const float4*)&zt[r * 4 + 3][(KB) + k];               \
        float4 b0_ = *(const float4*)&wb[k + 0][c * 4];                      \
        float4 b1_ = *(const float4*)&wb[k + 1][c * 4];                      \
        float4 b2_ = *(const float4*)&wb[k + 2][c * 4];                      \
        float4 b3_ = *(const float4*)&wb[k + 3][c * 4];                      \
        acc00 = fmaf(a0_.x, b0_.x, acc00); acc01 = fmaf(a0_.x, b0_.y, acc01);\
        acc02 = fmaf(a0_.x, b0_.z, acc02); acc03 = fmaf(a0_.x, b0_.w, acc03);\
        acc00 = fmaf(a0_.y, b1_.x, acc00); acc01 = fmaf(a0_.y, b1_.y, acc01);\
        acc02 = fmaf(a0_.y, b1_.z, acc02); acc03 = fmaf(a0_.y, b1_.w, acc03);\
        acc00 = fmaf(a0_.z, b2_.x, acc00); acc01 = fmaf(a0_.z, b2_.y, acc01);\
        acc02 = fmaf(a0_.z, b2_.z, acc02); acc03 = fmaf(a0_.z, b2_.w, acc03);\
        acc00 = fmaf(a0_.w, b3_.x, acc00); acc01 = fmaf(a0_.w, b3_.y, acc01);\
        acc02 = fmaf(a0_.w, b3_.z, acc02); acc03 = fmaf(a0_.w, b3_.w, acc03);\
        acc10 = fmaf(a1_.x, b0_.x, acc10); acc11 = fmaf(a1_.x, b0_.y, acc11);\
        acc12 = fmaf(a1_.x, b0_.z, acc12); acc13 = fmaf(a1_.x, b0_.w, acc13);\
        acc10 = fmaf(a1_.y, b1_.x, acc10); acc11 = fmaf(a1_.y, b1_.y, acc11);\
        acc12 = fmaf(a1_.y, b1_.z, acc12); acc13 = fmaf(a1_.y, b1_.w, acc13);\
        acc10 = fmaf(a1_.z, b2_.x, acc10); acc11 = fmaf(a1_.z, b2_.y, acc11);\
        acc12 = fmaf(a1_.z, b2_.z, acc12); acc13 = fmaf(a1_.z, b2_.w, acc13);\
        acc10 = fmaf(a1_.w, b3_.x, acc10); acc11 = fmaf(a1_.w, b3_.y, acc11);\
        acc12 = fmaf(a1_.w, b3_.z, acc12); acc13 = fmaf(a1_.w, b3_.w, acc13);\
        acc20 = fmaf(a2_.x, b0_.x, acc20); acc21 = fmaf(a2_.x, b0_.y, acc21);\
        acc22 = fmaf(a2_.x, b0_.z, acc22); acc23 = fmaf(a2_.x, b0_.w, acc23);\
        acc20 = fmaf(a2_.y, b1_.x, acc20); acc21 = fmaf(a2_.y, b1_.y, acc21);\
        acc22 = fmaf(a2_.y, b1_.z, acc22); acc23 = fmaf(a2_.y, b1_.w, acc23);\
        acc20 = fmaf(a2_.z, b2_.x, acc20); acc21 = fmaf(a2_.z, b2_.y, acc21);\
        acc22 = fmaf(a2_.z, b2_.z, acc22); acc23 = fmaf(a2_.z, b2_.w, acc23);\
        acc20 = fmaf(a2_.w, b3_.x, acc20); acc21 = fmaf(a2_.w, b3_.y, acc21);\
        acc22 = fmaf(a2_.w, b3_.z, acc22); acc23 = fmaf(a2_.w, b3_.w, acc23);\
        acc30 = fmaf(a3_.x, b0_.x, acc30); acc31 = fmaf(a3_.x, b0_.y, acc31);\
        acc32 = fmaf(a3_.x, b0_.z, acc32); acc33 = fmaf(a3_.x, b0_.w, acc33);\
        acc30 = fmaf(a3_.y, b1_.x, acc30); acc31 = fmaf(a3_.y, b1_.y, acc31);\
        acc32 = fmaf(a3_.y, b1_.z, acc32); acc33 = fmaf(a3_.y, b1_.w, acc33);\
        acc30 = fmaf(a3_.z, b2_.x, acc30); acc31 = fmaf(a3_.z, b2_.y, acc31);\
        acc32 = fmaf(a3_.z, b2_.z, acc32); acc33 = fmaf(a3_.z, b2_.w, acc33);\
        acc30 = fmaf(a3_.w, b3_.x, acc30); acc31 = fmaf(a3_.w, b3_.y, acc31);\
        acc32 = fmaf(a3_.w, b3_.z, acc32); acc33 = fmaf(a3_.w, b3_.w, acc33);\
    }

#define ACC_ZERO()                                                           \
    acc00 = acc01 = acc02 = acc03 = 0.f;                                     \
    acc10 = acc11 = acc12 = acc13 = 0.f;                                     \
    acc20 = acc21 = acc22 = acc23 = 0.f;                                     \
    acc30 = acc31 = acc32 = acc33 = 0.f;

// -------------------- MLP in-place: z = relu(zW1+b1)W2+b2, + BN stats ----
// W staged in LDS in two 32 KB K-halves -> 48 KB LDS -> 3 blocks/CU.
// All inner-loop state in named scalar registers (no arrays, no fn calls):
// round-7/8 showed helper fns w/ array params put acc in scratch (2 GB/disp).
__global__ __launch_bounds__(256, 3) void k_mlp(float* __restrict__ z,
                                                const float* __restrict__ W1,
                                                const float* __restrict__ b1,
                                                const float* __restrict__ W2,
                                                const float* __restrict__ b2,
                                                float* __restrict__ bnsum,
                                                float* __restrict__ bnsq) {
    __shared__ float zt[TM][DIM];   // 16 KB: A tile -> y1 tile -> stats scratch
    __shared__ float wb[KH][DIM];   // 32 KB: W K-half buffer
    const int t = threadIdx.x;
    const int c = t & 31;           // output cols 4c..4c+3
    const int r = t >> 5;           // row group: rows 4r..4r+3
    const int row0 = blockIdx.x * TM;

    // ---- load z tile + stage W1 rows 0..63 ----
    #pragma unroll
    for (int i = 0; i < 4; ++i) {
        int f4 = t + i * 256;
        int rr = f4 >> 5, c4 = f4 & 31;
        int g  = row0 + rr;
        float4 v = make_float4(0.f, 0.f, 0.f, 0.f);
        if (g < NN) v = *(const float4*)&z[(size_t)g * DIM + c4 * 4];
        *(float4*)&zt[rr][c4 * 4] = v;
    }
    STAGE_W(W1);
    __syncthreads();

    float acc00, acc01, acc02, acc03, acc10, acc11, acc12, acc13;
    float acc20, acc21, acc22, acc23, acc30, acc31, acc32, acc33;

    // ---- GEMM1 ----
    ACC_ZERO();
    GEMM_HALF(0);
    __syncthreads();                 // wb reads done
    STAGE_W(W1 + KH * DIM);          // W1 rows 64..127
    __syncthreads();
    GEMM_HALF(KH);
    __syncthreads();                 // zt reads done (pre-overwrite)

    // ---- bias1 + relu -> y1 into zt; stage W2 rows 0..63 ----
    {
        const float4 bias1 = *(const float4*)&b1[c * 4];
        float4 y;
        y.x = fmaxf(acc00 + bias1.x, 0.f); y.y = fmaxf(acc01 + bias1.y, 0.f);
        y.z = fmaxf(acc02 + bias1.z, 0.f); y.w = fmaxf(acc03 + bias1.w, 0.f);
        *(float4*)&zt[r * 4 + 0][c * 4] = y;
        y.x = fmaxf(acc10 + bias1.x, 0.f); y.y = fmaxf(acc11 + bias1.y, 0.f);
        y.z = fmaxf(acc12 + bias1.z, 0.f); y.w = fmaxf(acc13 + bias1.w, 0.f);
        *(float4*)&zt[r * 4 + 1][c * 4] = y;
        y.x = fmaxf(acc20 + bias1.x, 0.f); y.y = fmaxf(acc21 + bias1.y, 0.f);
        y.z = fmaxf(acc22 + bias1.z, 0.f); y.w = fmaxf(acc23 + bias1.w, 0.f);
        *(float4*)&zt[r * 4 + 2][c * 4] = y;
        y.x = fmaxf(acc30 + bias1.x, 0.f); y.y = fmaxf(acc31 + bias1.y, 0.f);
        y.z = fmaxf(acc32 + bias1.z, 0.f); y.w = fmaxf(acc33 + bias1.w, 0.f);
        *(float4*)&zt[r * 4 + 3][c * 4] = y;
    }
    STAGE_W(W2);
    __syncthreads();

    // ---- GEMM2 ----
    ACC_ZERO();
    GEMM_HALF(0);
    __syncthreads();                 // wb reads done
    STAGE_W(W2 + KH * DIM);          // W2 rows 64..127
    __syncthreads();
    GEMM_HALF(KH);
    __syncthreads();                 // zt reads done (pre-scratch reuse)

    // ---- bias2, write z (pre-BN) in place, block stats -> atomics ----
    const float4 bias2 = *(const float4*)&b2[c * 4];
    float s0 = 0.f, s1 = 0.f, s2 = 0.f, s3 = 0.f;
    float q0 = 0.f, q1 = 0.f, q2 = 0.f, q3 = 0.f;
    #define EPILOG_ROW(I, A0, A1, A2, A3)                                    \
    {                                                                        \
        int g = row0 + r * 4 + I;                                            \
        float4 zv;                                                           \
        zv.x = A0 + bias2.x; zv.y = A1 + bias2.y;                            \
        zv.z = A2 + bias2.z; zv.w = A3 + bias2.w;                            \
        if (g < NN) {                                                        \
            *(float4*)&z[(size_t)g * DIM + c * 4] = zv;                      \
            s0 += zv.x; s1 += zv.y; s2 += zv.z; s3 += zv.w;                  \
            q0 += zv.x * zv.x; q1 += zv.y * zv.y;                            \
            q2 += zv.z * zv.z; q3 += zv.w * zv.w;                            \
        }                                                                    \
    }
    EPILOG_ROW(0, acc00, acc01, acc02, acc03);
    EPILOG_ROW(1, acc10, acc11, acc12, acc13);
    EPILOG_ROW(2, acc20, acc21, acc22, acc23);
    EPILOG_ROW(3, acc30, acc31, acc32, acc33);
    #undef EPILOG_ROW

    float* scratch = &zt[0][0];     // [0:1024)=sum, [1024:2048)=sq
    scratch[r * DIM + c * 4 + 0] = s0;
    scratch[r * DIM + c * 4 + 1] = s1;
    scratch[r * DIM + c * 4 + 2] = s2;
    scratch[r * DIM + c * 4 + 3] = s3;
    scratch[1024 + r * DIM + c * 4 + 0] = q0;
    scratch[1024 + r * DIM + c * 4 + 1] = q1;
    scratch[1024 + r * DIM + c * 4 + 2] = q2;
    scratch[1024 + r * DIM + c * 4 + 3] = q3;
    __syncthreads();
    if (t < DIM) {
        float ss = 0.f, qq = 0.f;
        #pragma unroll
        for (int rr = 0; rr < 8; ++rr) {
            ss += scratch[rr * DIM + t];
            qq += scratch[1024 + rr * DIM + t];
        }
        atomicAdd(&bnsum[t], ss);
        atomicAdd(&bnsq[t], qq);
    }
}

// ------------- final FC with fused last-layer norm (per-lane sc/sh) ----
__global__ __launch_bounds__(256) void k_fc(const float* __restrict__ z,
                                            const float* __restrict__ bnsum,
                                            const float* __restrict__ bnsq,
                                            const float* __restrict__ gamma,
                                            const float* __restrict__ beta,
                                            const float* __restrict__ fc_w,
                                            const float* __restrict__ fc_b,
                                            float* __restrict__ out) {
    int wid  = (blockIdx.x * 256 + threadIdx.x) >> 6;
    int lane = threadIdx.x & 63;
    if (wid >= NN) return;
    const int j0 = lane * 2;
    const float invN = 1.0f / (float)NN;
    float mu0 = bnsum[j0] * invN;
    float mu1 = bnsum[j0 + 1] * invN;
    float k0 = rsqrtf(bnsq[j0] * invN - mu0 * mu0 + BN_EPS) * gamma[j0];
    float k1 = rsqrtf(bnsq[j0 + 1] * invN - mu1 * mu1 + BN_EPS) * gamma[j0 + 1];
    float sh0 = beta[j0] - mu0 * k0;
    float sh1 = beta[j0 + 1] - mu1 * k1;

    float2 v = *(const float2*)&z[(size_t)wid * DIM + lane * 2];
    v.x = fmaxf(fmaf(v.x, k0, sh0), 0.f);
    v.y = fmaxf(fmaf(v.y, k1, sh1), 0.f);
    float2 wv = *(const float2*)&fc_w[lane * 2];
    float s = v.x * wv.x + v.y * wv.y;
    #pragma unroll
    for (int o = 32; o >= 1; o >>= 1) s += __shfl_down(s, o);
    if (lane == 0) out[wid] = s + fc_b[0];
}

// -------------------------------------------------------------- launch ----
extern "C" void kernel_launch(void* const* d_in, const int* in_sizes, int n_in,
                              void* d_out, int out_size, void* d_ws, size_t ws_size,
                              hipStream_t stream) {
    const float* x     = (const float*)d_in[0];
    const int*   src   = (const int*)d_in[1];          // edge_index[0]
    const int*   dst   = ((const int*)d_in[1]) + NE;   // edge_index[1]
    const float* W1    = (const float*)d_in[2];
    const float* b1    = (const float*)d_in[3];
    const float* W2    = (const float*)d_in[4];
    const float* b2    = (const float*)d_in[5];
    const float* gamma = (const float*)d_in[6];
    const float* beta  = (const float*)d_in[7];
    const float* fc_w  = (const float*)d_in[8];
    const float* fc_b  = (const float*)d_in[9];
    float* out = (float*)d_out;

    // workspace carve (16B aligned chunks)
    char* ws = (char*)d_ws;
    size_t o = 0;
    auto carve = [&](size_t bytes) {
        char* p = ws + o;
        o += (bytes + 15) & ~(size_t)15;
        return p;
    };
    int*   deg     = (int*)carve(NN * 4);
    int*   off     = (int*)carve((NN + 1) * 4);
    int*   cur     = (int*)carve(NN * 4);
    int*   csr     = (int*)carve(NE * 4);
    int*   part    = (int*)carve(NN * 4);
    int*   bsum    = (int*)carve(NSCAN * 4);
    int*   boff    = (int*)carve(NSCAN * 4);
    float* bnstats = (float*)carve(LAYERS * 2 * DIM * 4);  // [sum(3x128) | sq(3x128)]
    float* zA      = (float*)carve((size_t)NN * DIM * 4);
    float* zB      = (float*)carve((size_t)NN * DIM * 4);

    // ---- CSR build (once per call) ----
    k_init<<<(NN + 255) / 256, 256, 0, stream>>>(deg, bnstats);
    k_hist<<<(NE + 255) / 256, 256, 0, stream>>>(dst, deg);
    k_scan1<<<NSCAN, 1024, 0, stream>>>(deg, part, bsum);
    k_scan2<<<1, 64, 0, stream>>>(bsum, boff);
    k_scan3<<<(NN + 255) / 256, 256, 0, stream>>>(part, boff, off, cur);
    k_fill<<<(NE + 255) / 256, 256, 0, stream>>>(src, dst, cur, csr);

    // ---- layers: agg(norm-fused) -> mlp(in-place) ----
    const int nblk_mlp = (NN + TM - 1) / TM;
    const int nblk_agg = (NN * 64 + 255) / 256;
    float* zbuf[2] = {zA, zB};
    for (int l = 0; l < LAYERS; ++l) {
        const float* hin = (l == 0) ? x : zbuf[(l + 1) & 1];
        float* zo = zbuf[l & 1];
        float* sum_l = bnstats + l * DIM;
        float* sq_l  = bnstats + LAYERS * DIM + l * DIM;
        const float* sum_p = bnstats + (l - 1) * DIM;
        const float* sq_p  = bnstats + LAYERS * DIM + (l - 1) * DIM;
        if (l == 0)
            k_agg<0><<<nblk_agg, 256, 0, stream>>>(hin, nullptr, nullptr, nullptr,
                                                   nullptr, off, csr, zo);
        else
            k_agg<1><<<nblk_agg, 256, 0, stream>>>(hin, sum_p, sq_p,
                                                   gamma + (l - 1) * DIM,
                                                   beta + (l - 1) * DIM,
                                                   off, csr, zo);
        k_mlp<<<nblk_mlp, 256, 0, stream>>>(zo,
                                            W1 + (size_t)l * DIM * DIM, b1 + l * DIM,
                                            W2 + (size_t)l * DIM * DIM, b2 + l * DIM,
                                            sum_l, sq_l);
    }

    // ---- final FC (fused last norm) ----
    k_fc<<<(NN * 64 + 255) / 256, 256, 0, stream>>>(zbuf[(LAYERS + 1) & 1],
                                                    bnstats + (LAYERS - 1) * DIM,
                                                    bnstats + (2 * LAYERS - 1) * DIM,
                                                    gamma + (LAYERS - 1) * DIM,
                                                    beta + (LAYERS - 1) * DIM,
                                                    fc_w, fc_b, out);
}